// Round 1
// baseline (1003.808 us; speedup 1.0000x reference)
//
#include <hip/hip_runtime.h>
#include <math.h>

// Problem constants (derived at runtime from in_sizes too)
#define CH 256   // IN_CH == HID == 256

// ---------------------------------------------------------------------------
// 1. Histogram: cnt_src[n] = #edges with src==n ; cnt_dst[n] = #edges dst==n
// ---------------------------------------------------------------------------
__global__ void hist_kernel(const int* __restrict__ ei,
                            unsigned* __restrict__ cnt_src,
                            unsigned* __restrict__ cnt_dst, int E) {
    int i = blockIdx.x * blockDim.x + threadIdx.x;
    int stride = gridDim.x * blockDim.x;
    for (; i < E; i += stride) {
        atomicAdd(&cnt_src[ei[i]], 1u);
        atomicAdd(&cnt_dst[ei[E + i]], 1u);
    }
}

// ---------------------------------------------------------------------------
// 2. Single-block exclusive scan of cnt_dst -> row_ptr, cursor; dinv=rsqrt(deg)
//    deg = cnt_src + 1 (self loop), always > 0.
// ---------------------------------------------------------------------------
__global__ void scan_kernel(const unsigned* __restrict__ cnt_src,
                            const unsigned* __restrict__ cnt_dst,
                            unsigned* __restrict__ row_ptr,
                            unsigned* __restrict__ cursor,
                            float* __restrict__ dinv, int N) {
    __shared__ unsigned tot[257];
    int t = threadIdx.x;
    int chunk = (N + 255) / 256;
    int lo = t * chunk;
    int hi = min(lo + chunk, N);
    unsigned local = 0;
    for (int i = lo; i < hi; i++) local += cnt_dst[i];
    tot[t] = local;
    __syncthreads();
    if (t == 0) {
        unsigned run = 0;
        for (int i = 0; i < 256; i++) { unsigned v = tot[i]; tot[i] = run; run += v; }
        tot[256] = run;
        row_ptr[N] = run;
    }
    __syncthreads();
    unsigned run = tot[t];
    for (int i = lo; i < hi; i++) {
        row_ptr[i] = run;
        cursor[i]  = run;
        run += cnt_dst[i];
        dinv[i] = rsqrtf((float)(cnt_src[i] + 1u));
    }
}

// ---------------------------------------------------------------------------
// 3. CSR fill: col[] holds src node ids grouped by dst
// ---------------------------------------------------------------------------
__global__ void fill_kernel(const int* __restrict__ ei,
                            unsigned* __restrict__ cursor,
                            unsigned* __restrict__ col, int E) {
    int i = blockIdx.x * blockDim.x + threadIdx.x;
    int stride = gridDim.x * blockDim.x;
    for (; i < E; i += stride) {
        int d = ei[E + i];
        unsigned pos = atomicAdd(&cursor[d], 1u);
        col[pos] = (unsigned)ei[i];
    }
}

// ---------------------------------------------------------------------------
// 4. y = dinv[:,None] * (x @ W)   fp32, 32-row x 256-col tile per 256-thr block
//    thread: 8 rows x 4 cols, K staged in LDS chunks of 32.
// ---------------------------------------------------------------------------
__global__ __launch_bounds__(256) void gemm_kernel(const float* __restrict__ x,
                                                   const float* __restrict__ W,
                                                   const float* __restrict__ dinv,
                                                   float* __restrict__ y, int M) {
    __shared__ float xs[32][32];     // 4 KB
    __shared__ float wsm[32][CH];    // 32 KB
    int t  = threadIdx.x;
    int m0 = blockIdx.x * 32;
    int c0 = (t & 63) * 4;           // column group
    int r0 = (t >> 6) * 8;           // row group
    float acc[8][4];
#pragma unroll
    for (int i = 0; i < 8; i++)
#pragma unroll
        for (int j = 0; j < 4; j++) acc[i][j] = 0.f;

    int xr = t >> 3, xk = (t & 7) << 2;
    for (int k0 = 0; k0 < CH; k0 += 32) {
        // prefetch to regs
        float4 xv = make_float4(0.f, 0.f, 0.f, 0.f);
        if (m0 + xr < M) xv = *(const float4*)&x[(size_t)(m0 + xr) * CH + k0 + xk];
        float4 wv[8];
#pragma unroll
        for (int i = 0; i < 8; i++) {
            int idx = t + i * 256;
            int kr = idx >> 6, cq = (idx & 63) << 2;
            wv[i] = *(const float4*)&W[(size_t)(k0 + kr) * CH + cq];
        }
        __syncthreads();
        *(float4*)&xs[xr][xk] = xv;
#pragma unroll
        for (int i = 0; i < 8; i++) {
            int idx = t + i * 256;
            int kr = idx >> 6, cq = (idx & 63) << 2;
            *(float4*)&wsm[kr][cq] = wv[i];
        }
        __syncthreads();
#pragma unroll
        for (int k = 0; k < 32; k += 4) {
            float4 w0 = *(float4*)&wsm[k + 0][c0];
            float4 w1 = *(float4*)&wsm[k + 1][c0];
            float4 w2 = *(float4*)&wsm[k + 2][c0];
            float4 w3 = *(float4*)&wsm[k + 3][c0];
#pragma unroll
            for (int i = 0; i < 8; i++) {
                float4 xv4 = *(float4*)&xs[r0 + i][k];
                acc[i][0] += xv4.x * w0.x + xv4.y * w1.x + xv4.z * w2.x + xv4.w * w3.x;
                acc[i][1] += xv4.x * w0.y + xv4.y * w1.y + xv4.z * w2.y + xv4.w * w3.y;
                acc[i][2] += xv4.x * w0.z + xv4.y * w1.z + xv4.z * w2.z + xv4.w * w3.z;
                acc[i][3] += xv4.x * w0.w + xv4.y * w1.w + xv4.z * w2.w + xv4.w * w3.w;
            }
        }
    }
#pragma unroll
    for (int i = 0; i < 8; i++) {
        int m = m0 + r0 + i;
        if (m < M) {
            float dv = dinv[m];
            float4 o = make_float4(dv * acc[i][0], dv * acc[i][1],
                                   dv * acc[i][2], dv * acc[i][3]);
            *(float4*)&y[(size_t)m * CH + c0] = o;
        }
    }
}

// ---------------------------------------------------------------------------
// 5. Fused gather + bias + relu + node-sum. One wave per node (grid-stride),
//    lane owns channels 4L..4L+3. Block writes 256 partial sums (no atomics).
// ---------------------------------------------------------------------------
__global__ __launch_bounds__(256) void gather_kernel(const float* __restrict__ y,
                                                     const unsigned* __restrict__ row_ptr,
                                                     const unsigned* __restrict__ col,
                                                     const float* __restrict__ dinv,
                                                     const float* __restrict__ bias,
                                                     float* __restrict__ partials, int N) {
    int t = threadIdx.x;
    int lane = t & 63, wv = t >> 6;
    int gw = blockIdx.x * 4 + wv;
    int nw = gridDim.x * 4;
    float4 b4 = *(const float4*)&bias[lane * 4];
    float4 ts = make_float4(0.f, 0.f, 0.f, 0.f);

    for (int n = gw; n < N; n += nw) {
        unsigned rp0 = row_ptr[n], rp1 = row_ptr[n + 1];
        float dv = dinv[n];
        float4 a0 = ((const float4*)&y[(size_t)n * CH])[lane];  // self loop
        float4 a1 = make_float4(0.f, 0.f, 0.f, 0.f);
        unsigned e = rp0;
        for (; e + 1 < rp1; e += 2) {
            unsigned s0 = col[e], s1 = col[e + 1];
            float4 v0 = ((const float4*)&y[(size_t)s0 * CH])[lane];
            float4 v1 = ((const float4*)&y[(size_t)s1 * CH])[lane];
            a0.x += v0.x; a0.y += v0.y; a0.z += v0.z; a0.w += v0.w;
            a1.x += v1.x; a1.y += v1.y; a1.z += v1.z; a1.w += v1.w;
        }
        if (e < rp1) {
            unsigned s0 = col[e];
            float4 v0 = ((const float4*)&y[(size_t)s0 * CH])[lane];
            a0.x += v0.x; a0.y += v0.y; a0.z += v0.z; a0.w += v0.w;
        }
        float4 h;
        h.x = fmaxf(dv * (a0.x + a1.x) + b4.x, 0.f);
        h.y = fmaxf(dv * (a0.y + a1.y) + b4.y, 0.f);
        h.z = fmaxf(dv * (a0.z + a1.z) + b4.z, 0.f);
        h.w = fmaxf(dv * (a0.w + a1.w) + b4.w, 0.f);
        ts.x += h.x; ts.y += h.y; ts.z += h.z; ts.w += h.w;
    }

    __shared__ float red[1024];
    *(float4*)&red[wv * 256 + lane * 4] = ts;
    __syncthreads();
    if (t < 256) {
        partials[(size_t)blockIdx.x * 256 + t] =
            red[t] + red[256 + t] + red[512 + t] + red[768 + t];
    }
}

// ---------------------------------------------------------------------------
// 6. Sum partials -> s[256]; four tanh(s @ w.T + b) heads, out = concat(768)
// ---------------------------------------------------------------------------
__global__ __launch_bounds__(256) void final_kernel(const float* __restrict__ partials, int nblk,
                                                    const float* __restrict__ fc1_w, const float* __restrict__ fc1_b,
                                                    const float* __restrict__ fc2_w, const float* __restrict__ fc2_b,
                                                    const float* __restrict__ fc3_w, const float* __restrict__ fc3_b,
                                                    const float* __restrict__ fc4_w, const float* __restrict__ fc4_b,
                                                    float* __restrict__ out) {
    __shared__ float s[256];
    int t = threadIdx.x;
    float v = 0.f;
    for (int b = 0; b < nblk; b++) v += partials[(size_t)b * 256 + t];
    s[t] = v;
    __syncthreads();

    float d1 = fc1_b[t], d2 = fc2_b[t];
    for (int k = 0; k < 256; k += 4) {
        float4 w1 = *(const float4*)&fc1_w[(size_t)t * 256 + k];
        float4 w2 = *(const float4*)&fc2_w[(size_t)t * 256 + k];
        d1 += s[k] * w1.x + s[k + 1] * w1.y + s[k + 2] * w1.z + s[k + 3] * w1.w;
        d2 += s[k] * w2.x + s[k + 1] * w2.y + s[k + 2] * w2.z + s[k + 3] * w2.w;
    }
    out[t]       = tanhf(d1);
    out[256 + t] = tanhf(d2);
    if (t < 128) {
        float d3 = fc3_b[t], d4 = fc4_b[t];
        for (int k = 0; k < 256; k += 4) {
            float4 w3 = *(const float4*)&fc3_w[(size_t)t * 256 + k];
            float4 w4 = *(const float4*)&fc4_w[(size_t)t * 256 + k];
            d3 += s[k] * w3.x + s[k + 1] * w3.y + s[k + 2] * w3.z + s[k + 3] * w3.w;
            d4 += s[k] * w4.x + s[k + 1] * w4.y + s[k + 2] * w4.z + s[k + 3] * w4.w;
        }
        out[512 + t] = tanhf(d3);
        out[640 + t] = tanhf(d4);
    }
}

// ---------------------------------------------------------------------------
extern "C" void kernel_launch(void* const* d_in, const int* in_sizes, int n_in,
                              void* d_out, int out_size, void* d_ws, size_t ws_size,
                              hipStream_t stream) {
    const float* x      = (const float*)d_in[0];
    const int*   ei     = (const int*)d_in[1];
    const float* conv_w = (const float*)d_in[2];
    const float* conv_b = (const float*)d_in[3];
    const float* fc1_w  = (const float*)d_in[4];
    const float* fc1_b  = (const float*)d_in[5];
    const float* fc2_w  = (const float*)d_in[6];
    const float* fc2_b  = (const float*)d_in[7];
    const float* fc3_w  = (const float*)d_in[8];
    const float* fc3_b  = (const float*)d_in[9];
    const float* fc4_w  = (const float*)d_in[10];
    const float* fc4_b  = (const float*)d_in[11];
    float* out = (float*)d_out;

    const int N = in_sizes[0] / CH;   // 50000
    const int E = in_sizes[1] / 2;    // 800000

    // workspace carve-out (256B aligned)
    char* ws = (char*)d_ws;
    size_t off = 0;
    auto alloc = [&](size_t bytes) -> void* {
        off = (off + 255) & ~(size_t)255;
        void* p = ws + off;
        off += bytes;
        return p;
    };
    unsigned* cnt_src = (unsigned*)alloc((size_t)N * 4);
    unsigned* cnt_dst = (unsigned*)alloc((size_t)N * 4);
    unsigned* row_ptr = (unsigned*)alloc((size_t)(N + 1) * 4);
    unsigned* cursor  = (unsigned*)alloc((size_t)N * 4);
    float*    dinv    = (float*)alloc((size_t)N * 4);
    unsigned* col     = (unsigned*)alloc((size_t)E * 4);
    float*    y       = (float*)alloc((size_t)N * CH * 4);
    const int GBLK = 1024;
    float*    partials = (float*)alloc((size_t)GBLK * 256 * 4);

    hipMemsetAsync(cnt_src, 0, (size_t)N * 4, stream);
    hipMemsetAsync(cnt_dst, 0, (size_t)N * 4, stream);

    hist_kernel<<<1024, 256, 0, stream>>>(ei, cnt_src, cnt_dst, E);
    scan_kernel<<<1, 256, 0, stream>>>(cnt_src, cnt_dst, row_ptr, cursor, dinv, N);
    fill_kernel<<<1024, 256, 0, stream>>>(ei, cursor, col, E);
    gemm_kernel<<<(N + 31) / 32, 256, 0, stream>>>(x, conv_w, dinv, y, N);
    gather_kernel<<<GBLK, 256, 0, stream>>>(y, row_ptr, col, dinv, conv_b, partials, N);
    final_kernel<<<1, 256, 0, stream>>>(partials, GBLK,
                                        fc1_w, fc1_b, fc2_w, fc2_b,
                                        fc3_w, fc3_b, fc4_w, fc4_b, out);
}

// Round 2
// 744.508 us; speedup vs baseline: 1.3483x; 1.3483x over previous
//
#include <hip/hip_runtime.h>
#include <math.h>

#define CH 256   // IN_CH == HID == 256

// ---------------------------------------------------------------------------
// 1. Histogram: cnt_src[n] = #edges with src==n ; cnt_dst[n] = #edges dst==n
// ---------------------------------------------------------------------------
__global__ void hist_kernel(const int* __restrict__ ei,
                            unsigned* __restrict__ cnt_src,
                            unsigned* __restrict__ cnt_dst, int E) {
    int i = blockIdx.x * blockDim.x + threadIdx.x;
    int stride = gridDim.x * blockDim.x;
    for (; i < E; i += stride) {
        atomicAdd(&cnt_src[ei[i]], 1u);
        atomicAdd(&cnt_dst[ei[E + i]], 1u);
    }
}

// ---------------------------------------------------------------------------
// 2. Single-block exclusive scan of cnt_dst -> row_ptr, cursor; dinv=rsqrt(deg)
// ---------------------------------------------------------------------------
__global__ void scan_kernel(const unsigned* __restrict__ cnt_src,
                            const unsigned* __restrict__ cnt_dst,
                            unsigned* __restrict__ row_ptr,
                            unsigned* __restrict__ cursor,
                            float* __restrict__ dinv, int N) {
    __shared__ unsigned tot[257];
    int t = threadIdx.x;
    int chunk = (N + 255) / 256;
    int lo = t * chunk;
    int hi = min(lo + chunk, N);
    unsigned local = 0;
    for (int i = lo; i < hi; i++) local += cnt_dst[i];
    tot[t] = local;
    __syncthreads();
    if (t == 0) {
        unsigned run = 0;
        for (int i = 0; i < 256; i++) { unsigned v = tot[i]; tot[i] = run; run += v; }
        tot[256] = run;
        row_ptr[N] = run;
    }
    __syncthreads();
    unsigned run = tot[t];
    for (int i = lo; i < hi; i++) {
        row_ptr[i] = run;
        cursor[i]  = run;
        run += cnt_dst[i];
        dinv[i] = rsqrtf((float)(cnt_src[i] + 1u));
    }
}

// ---------------------------------------------------------------------------
// 3. CSR fill: col[] holds src node ids grouped by dst
// ---------------------------------------------------------------------------
__global__ void fill_kernel(const int* __restrict__ ei,
                            unsigned* __restrict__ cursor,
                            unsigned* __restrict__ col, int E) {
    int i = blockIdx.x * blockDim.x + threadIdx.x;
    int stride = gridDim.x * blockDim.x;
    for (; i < E; i += stride) {
        int d = ei[E + i];
        unsigned pos = atomicAdd(&cursor[d], 1u);
        col[pos] = (unsigned)ei[i];
    }
}

// ---------------------------------------------------------------------------
// 4. y = dinv[:,None] * (x @ W)   fp32, 32-row x 256-col tile per 256-thr block
// ---------------------------------------------------------------------------
__global__ __launch_bounds__(256) void gemm_kernel(const float* __restrict__ x,
                                                   const float* __restrict__ W,
                                                   const float* __restrict__ dinv,
                                                   float* __restrict__ y, int M) {
    __shared__ float xs[32][32];     // 4 KB
    __shared__ float wsm[32][CH];    // 32 KB
    int t  = threadIdx.x;
    int m0 = blockIdx.x * 32;
    int c0 = (t & 63) * 4;           // column group
    int r0 = (t >> 6) * 8;           // row group
    float acc[8][4];
#pragma unroll
    for (int i = 0; i < 8; i++)
#pragma unroll
        for (int j = 0; j < 4; j++) acc[i][j] = 0.f;

    int xr = t >> 3, xk = (t & 7) << 2;
    for (int k0 = 0; k0 < CH; k0 += 32) {
        float4 xv = make_float4(0.f, 0.f, 0.f, 0.f);
        if (m0 + xr < M) xv = *(const float4*)&x[(size_t)(m0 + xr) * CH + k0 + xk];
        float4 wv[8];
#pragma unroll
        for (int i = 0; i < 8; i++) {
            int idx = t + i * 256;
            int kr = idx >> 6, cq = (idx & 63) << 2;
            wv[i] = *(const float4*)&W[(size_t)(k0 + kr) * CH + cq];
        }
        __syncthreads();
        *(float4*)&xs[xr][xk] = xv;
#pragma unroll
        for (int i = 0; i < 8; i++) {
            int idx = t + i * 256;
            int kr = idx >> 6, cq = (idx & 63) << 2;
            *(float4*)&wsm[kr][cq] = wv[i];
        }
        __syncthreads();
#pragma unroll
        for (int k = 0; k < 32; k += 4) {
            float4 w0 = *(float4*)&wsm[k + 0][c0];
            float4 w1 = *(float4*)&wsm[k + 1][c0];
            float4 w2 = *(float4*)&wsm[k + 2][c0];
            float4 w3 = *(float4*)&wsm[k + 3][c0];
#pragma unroll
            for (int i = 0; i < 8; i++) {
                float4 xv4 = *(float4*)&xs[r0 + i][k];
                acc[i][0] += xv4.x * w0.x + xv4.y * w1.x + xv4.z * w2.x + xv4.w * w3.x;
                acc[i][1] += xv4.x * w0.y + xv4.y * w1.y + xv4.z * w2.y + xv4.w * w3.y;
                acc[i][2] += xv4.x * w0.z + xv4.y * w1.z + xv4.z * w2.z + xv4.w * w3.z;
                acc[i][3] += xv4.x * w0.w + xv4.y * w1.w + xv4.z * w2.w + xv4.w * w3.w;
            }
        }
    }
#pragma unroll
    for (int i = 0; i < 8; i++) {
        int m = m0 + r0 + i;
        if (m < M) {
            float dv = dinv[m];
            float4 o = make_float4(dv * acc[i][0], dv * acc[i][1],
                                   dv * acc[i][2], dv * acc[i][3]);
            *(float4*)&y[(size_t)m * CH + c0] = o;
        }
    }
}

// ---------------------------------------------------------------------------
// 5. Fused gather + bias + relu + node-sum. One wave per node (grid-stride).
//    Block-reduces to 256 channel sums, then atomicAdd into s_sum[256].
// ---------------------------------------------------------------------------
__global__ __launch_bounds__(256) void gather_kernel(const float* __restrict__ y,
                                                     const unsigned* __restrict__ row_ptr,
                                                     const unsigned* __restrict__ col,
                                                     const float* __restrict__ dinv,
                                                     const float* __restrict__ bias,
                                                     float* __restrict__ s_sum, int N) {
    int t = threadIdx.x;
    int lane = t & 63, wv = t >> 6;
    int gw = blockIdx.x * 4 + wv;
    int nw = gridDim.x * 4;
    float4 b4 = *(const float4*)&bias[lane * 4];
    float4 ts = make_float4(0.f, 0.f, 0.f, 0.f);

    for (int n = gw; n < N; n += nw) {
        unsigned rp0 = row_ptr[n], rp1 = row_ptr[n + 1];
        float dv = dinv[n];
        float4 a0 = ((const float4*)&y[(size_t)n * CH])[lane];  // self loop
        float4 a1 = make_float4(0.f, 0.f, 0.f, 0.f);
        unsigned e = rp0;
        for (; e + 1 < rp1; e += 2) {
            unsigned s0 = col[e], s1 = col[e + 1];
            float4 v0 = ((const float4*)&y[(size_t)s0 * CH])[lane];
            float4 v1 = ((const float4*)&y[(size_t)s1 * CH])[lane];
            a0.x += v0.x; a0.y += v0.y; a0.z += v0.z; a0.w += v0.w;
            a1.x += v1.x; a1.y += v1.y; a1.z += v1.z; a1.w += v1.w;
        }
        if (e < rp1) {
            unsigned s0 = col[e];
            float4 v0 = ((const float4*)&y[(size_t)s0 * CH])[lane];
            a0.x += v0.x; a0.y += v0.y; a0.z += v0.z; a0.w += v0.w;
        }
        float4 h;
        h.x = fmaxf(dv * (a0.x + a1.x) + b4.x, 0.f);
        h.y = fmaxf(dv * (a0.y + a1.y) + b4.y, 0.f);
        h.z = fmaxf(dv * (a0.z + a1.z) + b4.z, 0.f);
        h.w = fmaxf(dv * (a0.w + a1.w) + b4.w, 0.f);
        ts.x += h.x; ts.y += h.y; ts.z += h.z; ts.w += h.w;
    }

    __shared__ float red[1024];
    *(float4*)&red[wv * 256 + lane * 4] = ts;
    __syncthreads();
    if (t < 256) {
        atomicAdd(&s_sum[t], red[t] + red[256 + t] + red[512 + t] + red[768 + t]);
    }
}

// ---------------------------------------------------------------------------
// 6. Parallel FC: one wave per output element (768 waves). Coalesced float4
//    dot-256 + shuffle reduce + tanh.
// ---------------------------------------------------------------------------
__global__ __launch_bounds__(256) void fc_kernel(const float* __restrict__ s_sum,
                                                 const float* __restrict__ fc1_w, const float* __restrict__ fc1_b,
                                                 const float* __restrict__ fc2_w, const float* __restrict__ fc2_b,
                                                 const float* __restrict__ fc3_w, const float* __restrict__ fc3_b,
                                                 const float* __restrict__ fc4_w, const float* __restrict__ fc4_b,
                                                 float* __restrict__ out) {
    int wid  = (blockIdx.x * blockDim.x + threadIdx.x) >> 6;  // global wave id
    int lane = threadIdx.x & 63;
    if (wid >= 768) return;
    const float* w; const float* b; int row, obase;
    if (wid < 256)      { w = fc1_w; b = fc1_b; row = wid;       obase = 0;   }
    else if (wid < 512) { w = fc2_w; b = fc2_b; row = wid - 256; obase = 256; }
    else if (wid < 640) { w = fc3_w; b = fc3_b; row = wid - 512; obase = 512; }
    else                { w = fc4_w; b = fc4_b; row = wid - 640; obase = 640; }
    float4 wv = *(const float4*)&w[(size_t)row * 256 + lane * 4];
    float4 sv = *(const float4*)&s_sum[lane * 4];
    float d = wv.x * sv.x + wv.y * sv.y + wv.z * sv.z + wv.w * sv.w;
#pragma unroll
    for (int off = 32; off; off >>= 1) d += __shfl_down(d, off, 64);
    if (lane == 0) out[obase + row] = tanhf(d + b[row]);
}

// ---------------------------------------------------------------------------
extern "C" void kernel_launch(void* const* d_in, const int* in_sizes, int n_in,
                              void* d_out, int out_size, void* d_ws, size_t ws_size,
                              hipStream_t stream) {
    const float* x      = (const float*)d_in[0];
    const int*   ei     = (const int*)d_in[1];
    const float* conv_w = (const float*)d_in[2];
    const float* conv_b = (const float*)d_in[3];
    const float* fc1_w  = (const float*)d_in[4];
    const float* fc1_b  = (const float*)d_in[5];
    const float* fc2_w  = (const float*)d_in[6];
    const float* fc2_b  = (const float*)d_in[7];
    const float* fc3_w  = (const float*)d_in[8];
    const float* fc3_b  = (const float*)d_in[9];
    const float* fc4_w  = (const float*)d_in[10];
    const float* fc4_b  = (const float*)d_in[11];
    float* out = (float*)d_out;

    const int N = in_sizes[0] / CH;   // 50000
    const int E = in_sizes[1] / 2;    // 800000

    char* ws = (char*)d_ws;
    size_t off = 0;
    auto alloc = [&](size_t bytes) -> void* {
        off = (off + 255) & ~(size_t)255;
        void* p = ws + off;
        off += bytes;
        return p;
    };
    unsigned* cnt_src = (unsigned*)alloc((size_t)N * 4);
    unsigned* cnt_dst = (unsigned*)alloc((size_t)N * 4);
    unsigned* row_ptr = (unsigned*)alloc((size_t)(N + 1) * 4);
    unsigned* cursor  = (unsigned*)alloc((size_t)N * 4);
    float*    dinv    = (float*)alloc((size_t)N * 4);
    unsigned* col     = (unsigned*)alloc((size_t)E * 4);
    float*    y       = (float*)alloc((size_t)N * CH * 4);
    float*    s_sum   = (float*)alloc((size_t)CH * 4);

    hipMemsetAsync(cnt_src, 0, (size_t)N * 4, stream);
    hipMemsetAsync(cnt_dst, 0, (size_t)N * 4, stream);
    hipMemsetAsync(s_sum,   0, (size_t)CH * 4, stream);

    hist_kernel<<<1024, 256, 0, stream>>>(ei, cnt_src, cnt_dst, E);
    scan_kernel<<<1, 256, 0, stream>>>(cnt_src, cnt_dst, row_ptr, cursor, dinv, N);
    fill_kernel<<<1024, 256, 0, stream>>>(ei, cursor, col, E);
    gemm_kernel<<<(N + 31) / 32, 256, 0, stream>>>(x, conv_w, dinv, y, N);
    gather_kernel<<<1024, 256, 0, stream>>>(y, row_ptr, col, dinv, conv_b, s_sum, N);
    fc_kernel<<<192, 256, 0, stream>>>(s_sum,
                                       fc1_w, fc1_b, fc2_w, fc2_b,
                                       fc3_w, fc3_b, fc4_w, fc4_b, out);
}

// Round 3
// 547.371 us; speedup vs baseline: 1.8339x; 1.3602x over previous
//
#include <hip/hip_runtime.h>
#include <math.h>

#define CH 256   // IN_CH == HID == 256

// ---------------------------------------------------------------------------
// 1. Histogram: cnt_src[n] = #edges with src==n ; cnt_dst[n] = #edges dst==n
// ---------------------------------------------------------------------------
__global__ void hist_kernel(const int* __restrict__ ei,
                            unsigned* __restrict__ cnt_src,
                            unsigned* __restrict__ cnt_dst, int E) {
    int i = blockIdx.x * blockDim.x + threadIdx.x;
    int stride = gridDim.x * blockDim.x;
    for (; i < E; i += stride) {
        atomicAdd(&cnt_src[ei[i]], 1u);
        atomicAdd(&cnt_dst[ei[E + i]], 1u);
    }
}

// ---------------------------------------------------------------------------
// 2a. Phase 1: per-block (1024-element chunk) reduction of cnt_dst -> bsum[b]
// ---------------------------------------------------------------------------
__global__ __launch_bounds__(256) void scan_p1(const unsigned* __restrict__ cnt_dst,
                                               unsigned* __restrict__ bsum, int N) {
    int b = blockIdx.x, t = threadIdx.x;
    int base = b * 1024 + t * 4;
    unsigned s = 0;
#pragma unroll
    for (int j = 0; j < 4; j++) {
        int i = base + j;
        if (i < N) s += cnt_dst[i];
    }
#pragma unroll
    for (int off = 32; off; off >>= 1) s += __shfl_down(s, off, 64);
    __shared__ unsigned wsum[4];
    if ((t & 63) == 0) wsum[t >> 6] = s;
    __syncthreads();
    if (t == 0) bsum[b] = wsum[0] + wsum[1] + wsum[2] + wsum[3];
}

// ---------------------------------------------------------------------------
// 2b. Phase 2: tiny serial scan of B block sums (B ~ 49)
// ---------------------------------------------------------------------------
__global__ void scan_p2(const unsigned* __restrict__ bsum,
                        unsigned* __restrict__ bbase,
                        unsigned* __restrict__ row_ptr, int B, int N) {
    if (threadIdx.x == 0 && blockIdx.x == 0) {
        unsigned run = 0;
        for (int b = 0; b < B; b++) { bbase[b] = run; run += bsum[b]; }
        row_ptr[N] = run;
    }
}

// ---------------------------------------------------------------------------
// 2c. Phase 3: per-chunk exclusive scan + dinv = rsqrt(cnt_src+1)
// ---------------------------------------------------------------------------
__global__ __launch_bounds__(256) void scan_p3(const unsigned* __restrict__ cnt_src,
                                               const unsigned* __restrict__ cnt_dst,
                                               const unsigned* __restrict__ bbase,
                                               unsigned* __restrict__ row_ptr,
                                               unsigned* __restrict__ cursor,
                                               float* __restrict__ dinv, int N) {
    int b = blockIdx.x, t = threadIdx.x;
    int base = b * 1024 + t * 4;
    unsigned v[4];
    unsigned tot = 0;
#pragma unroll
    for (int j = 0; j < 4; j++) {
        int i = base + j;
        v[j] = (i < N) ? cnt_dst[i] : 0u;
        tot += v[j];
    }
    __shared__ unsigned sc[256];
    sc[t] = tot;
    __syncthreads();
    // Hillis-Steele inclusive scan over 256 thread totals
    for (int off = 1; off < 256; off <<= 1) {
        unsigned x = (t >= off) ? sc[t - off] : 0u;
        __syncthreads();
        sc[t] += x;
        __syncthreads();
    }
    unsigned run = (t ? sc[t - 1] : 0u) + bbase[b];
#pragma unroll
    for (int j = 0; j < 4; j++) {
        int i = base + j;
        if (i < N) {
            row_ptr[i] = run;
            cursor[i]  = run;
            run += v[j];
            dinv[i] = rsqrtf((float)(cnt_src[i] + 1u));
        }
    }
}

// ---------------------------------------------------------------------------
// 3. CSR fill: col[] holds src node ids grouped by dst
// ---------------------------------------------------------------------------
__global__ void fill_kernel(const int* __restrict__ ei,
                            unsigned* __restrict__ cursor,
                            unsigned* __restrict__ col, int E) {
    int i = blockIdx.x * blockDim.x + threadIdx.x;
    int stride = gridDim.x * blockDim.x;
    for (; i < E; i += stride) {
        int d = ei[E + i];
        unsigned pos = atomicAdd(&cursor[d], 1u);
        col[pos] = (unsigned)ei[i];
    }
}

// ---------------------------------------------------------------------------
// 4. y = dinv[:,None] * (x @ W)   fp32, 32-row x 256-col tile per 256-thr block
// ---------------------------------------------------------------------------
__global__ __launch_bounds__(256) void gemm_kernel(const float* __restrict__ x,
                                                   const float* __restrict__ W,
                                                   const float* __restrict__ dinv,
                                                   float* __restrict__ y, int M) {
    __shared__ float xs[32][32];     // 4 KB
    __shared__ float wsm[32][CH];    // 32 KB
    int t  = threadIdx.x;
    int m0 = blockIdx.x * 32;
    int c0 = (t & 63) * 4;           // column group
    int r0 = (t >> 6) * 8;           // row group
    float acc[8][4];
#pragma unroll
    for (int i = 0; i < 8; i++)
#pragma unroll
        for (int j = 0; j < 4; j++) acc[i][j] = 0.f;

    int xr = t >> 3, xk = (t & 7) << 2;
    for (int k0 = 0; k0 < CH; k0 += 32) {
        float4 xv = make_float4(0.f, 0.f, 0.f, 0.f);
        if (m0 + xr < M) xv = *(const float4*)&x[(size_t)(m0 + xr) * CH + k0 + xk];
        float4 wv[8];
#pragma unroll
        for (int i = 0; i < 8; i++) {
            int idx = t + i * 256;
            int kr = idx >> 6, cq = (idx & 63) << 2;
            wv[i] = *(const float4*)&W[(size_t)(k0 + kr) * CH + cq];
        }
        __syncthreads();
        *(float4*)&xs[xr][xk] = xv;
#pragma unroll
        for (int i = 0; i < 8; i++) {
            int idx = t + i * 256;
            int kr = idx >> 6, cq = (idx & 63) << 2;
            *(float4*)&wsm[kr][cq] = wv[i];
        }
        __syncthreads();
#pragma unroll
        for (int k = 0; k < 32; k += 4) {
            float4 w0 = *(float4*)&wsm[k + 0][c0];
            float4 w1 = *(float4*)&wsm[k + 1][c0];
            float4 w2 = *(float4*)&wsm[k + 2][c0];
            float4 w3 = *(float4*)&wsm[k + 3][c0];
#pragma unroll
            for (int i = 0; i < 8; i++) {
                float4 xv4 = *(float4*)&xs[r0 + i][k];
                acc[i][0] += xv4.x * w0.x + xv4.y * w1.x + xv4.z * w2.x + xv4.w * w3.x;
                acc[i][1] += xv4.x * w0.y + xv4.y * w1.y + xv4.z * w2.y + xv4.w * w3.y;
                acc[i][2] += xv4.x * w0.z + xv4.y * w1.z + xv4.z * w2.z + xv4.w * w3.z;
                acc[i][3] += xv4.x * w0.w + xv4.y * w1.w + xv4.z * w2.w + xv4.w * w3.w;
            }
        }
    }
#pragma unroll
    for (int i = 0; i < 8; i++) {
        int m = m0 + r0 + i;
        if (m < M) {
            float dv = dinv[m];
            float4 o = make_float4(dv * acc[i][0], dv * acc[i][1],
                                   dv * acc[i][2], dv * acc[i][3]);
            *(float4*)&y[(size_t)m * CH + c0] = o;
        }
    }
}

// ---------------------------------------------------------------------------
// 5. Fused gather + bias + relu + node-sum. One wave per node (grid-stride).
//    Block-reduces to 256 channel sums, then atomicAdd into s_sum[256].
// ---------------------------------------------------------------------------
__global__ __launch_bounds__(256) void gather_kernel(const float* __restrict__ y,
                                                     const unsigned* __restrict__ row_ptr,
                                                     const unsigned* __restrict__ col,
                                                     const float* __restrict__ dinv,
                                                     const float* __restrict__ bias,
                                                     float* __restrict__ s_sum, int N) {
    int t = threadIdx.x;
    int lane = t & 63, wv = t >> 6;
    int gw = blockIdx.x * 4 + wv;
    int nw = gridDim.x * 4;
    float4 b4 = *(const float4*)&bias[lane * 4];
    float4 ts = make_float4(0.f, 0.f, 0.f, 0.f);

    for (int n = gw; n < N; n += nw) {
        unsigned rp0 = row_ptr[n], rp1 = row_ptr[n + 1];
        float dv = dinv[n];
        float4 a0 = ((const float4*)&y[(size_t)n * CH])[lane];  // self loop
        float4 a1 = make_float4(0.f, 0.f, 0.f, 0.f);
        unsigned e = rp0;
        for (; e + 1 < rp1; e += 2) {
            unsigned s0 = col[e], s1 = col[e + 1];
            float4 v0 = ((const float4*)&y[(size_t)s0 * CH])[lane];
            float4 v1 = ((const float4*)&y[(size_t)s1 * CH])[lane];
            a0.x += v0.x; a0.y += v0.y; a0.z += v0.z; a0.w += v0.w;
            a1.x += v1.x; a1.y += v1.y; a1.z += v1.z; a1.w += v1.w;
        }
        if (e < rp1) {
            unsigned s0 = col[e];
            float4 v0 = ((const float4*)&y[(size_t)s0 * CH])[lane];
            a0.x += v0.x; a0.y += v0.y; a0.z += v0.z; a0.w += v0.w;
        }
        float4 h;
        h.x = fmaxf(dv * (a0.x + a1.x) + b4.x, 0.f);
        h.y = fmaxf(dv * (a0.y + a1.y) + b4.y, 0.f);
        h.z = fmaxf(dv * (a0.z + a1.z) + b4.z, 0.f);
        h.w = fmaxf(dv * (a0.w + a1.w) + b4.w, 0.f);
        ts.x += h.x; ts.y += h.y; ts.z += h.z; ts.w += h.w;
    }

    __shared__ float red[1024];
    *(float4*)&red[wv * 256 + lane * 4] = ts;
    __syncthreads();
    if (t < 256) {
        atomicAdd(&s_sum[t], red[t] + red[256 + t] + red[512 + t] + red[768 + t]);
    }
}

// ---------------------------------------------------------------------------
// 6. Parallel FC: one wave per output element (768 waves).
// ---------------------------------------------------------------------------
__global__ __launch_bounds__(256) void fc_kernel(const float* __restrict__ s_sum,
                                                 const float* __restrict__ fc1_w, const float* __restrict__ fc1_b,
                                                 const float* __restrict__ fc2_w, const float* __restrict__ fc2_b,
                                                 const float* __restrict__ fc3_w, const float* __restrict__ fc3_b,
                                                 const float* __restrict__ fc4_w, const float* __restrict__ fc4_b,
                                                 float* __restrict__ out) {
    int wid  = (blockIdx.x * blockDim.x + threadIdx.x) >> 6;  // global wave id
    int lane = threadIdx.x & 63;
    if (wid >= 768) return;
    const float* w; const float* b; int row, obase;
    if (wid < 256)      { w = fc1_w; b = fc1_b; row = wid;       obase = 0;   }
    else if (wid < 512) { w = fc2_w; b = fc2_b; row = wid - 256; obase = 256; }
    else if (wid < 640) { w = fc3_w; b = fc3_b; row = wid - 512; obase = 512; }
    else                { w = fc4_w; b = fc4_b; row = wid - 640; obase = 640; }
    float4 wv = *(const float4*)&w[(size_t)row * 256 + lane * 4];
    float4 sv = *(const float4*)&s_sum[lane * 4];
    float d = wv.x * sv.x + wv.y * sv.y + wv.z * sv.z + wv.w * sv.w;
#pragma unroll
    for (int off = 32; off; off >>= 1) d += __shfl_down(d, off, 64);
    if (lane == 0) out[obase + row] = tanhf(d + b[row]);
}

// ---------------------------------------------------------------------------
extern "C" void kernel_launch(void* const* d_in, const int* in_sizes, int n_in,
                              void* d_out, int out_size, void* d_ws, size_t ws_size,
                              hipStream_t stream) {
    const float* x      = (const float*)d_in[0];
    const int*   ei     = (const int*)d_in[1];
    const float* conv_w = (const float*)d_in[2];
    const float* conv_b = (const float*)d_in[3];
    const float* fc1_w  = (const float*)d_in[4];
    const float* fc1_b  = (const float*)d_in[5];
    const float* fc2_w  = (const float*)d_in[6];
    const float* fc2_b  = (const float*)d_in[7];
    const float* fc3_w  = (const float*)d_in[8];
    const float* fc3_b  = (const float*)d_in[9];
    const float* fc4_w  = (const float*)d_in[10];
    const float* fc4_b  = (const float*)d_in[11];
    float* out = (float*)d_out;

    const int N = in_sizes[0] / CH;   // 50000
    const int E = in_sizes[1] / 2;    // 800000
    const int B = (N + 1023) / 1024;  // scan chunks (49)

    char* ws = (char*)d_ws;
    size_t off = 0;
    auto alloc = [&](size_t bytes) -> void* {
        off = (off + 255) & ~(size_t)255;
        void* p = ws + off;
        off += bytes;
        return p;
    };
    unsigned* cnt_src = (unsigned*)alloc((size_t)N * 4);
    unsigned* cnt_dst = (unsigned*)alloc((size_t)N * 4);
    unsigned* row_ptr = (unsigned*)alloc((size_t)(N + 1) * 4);
    unsigned* cursor  = (unsigned*)alloc((size_t)N * 4);
    float*    dinv    = (float*)alloc((size_t)N * 4);
    unsigned* col     = (unsigned*)alloc((size_t)E * 4);
    float*    y       = (float*)alloc((size_t)N * CH * 4);
    float*    s_sum   = (float*)alloc((size_t)CH * 4);
    unsigned* bsum    = (unsigned*)alloc((size_t)B * 4);
    unsigned* bbase   = (unsigned*)alloc((size_t)B * 4);

    hipMemsetAsync(cnt_src, 0, (size_t)N * 4, stream);
    hipMemsetAsync(cnt_dst, 0, (size_t)N * 4, stream);
    hipMemsetAsync(s_sum,   0, (size_t)CH * 4, stream);

    hist_kernel<<<1024, 256, 0, stream>>>(ei, cnt_src, cnt_dst, E);
    scan_p1<<<B, 256, 0, stream>>>(cnt_dst, bsum, N);
    scan_p2<<<1, 64, 0, stream>>>(bsum, bbase, row_ptr, B, N);
    scan_p3<<<B, 256, 0, stream>>>(cnt_src, cnt_dst, bbase, row_ptr, cursor, dinv, N);
    fill_kernel<<<1024, 256, 0, stream>>>(ei, cursor, col, E);
    gemm_kernel<<<(N + 31) / 32, 256, 0, stream>>>(x, conv_w, dinv, y, N);
    gather_kernel<<<1024, 256, 0, stream>>>(y, row_ptr, col, dinv, conv_b, s_sum, N);
    fc_kernel<<<192, 256, 0, stream>>>(s_sum,
                                       fc1_w, fc1_b, fc2_w, fc2_b,
                                       fc3_w, fc3_b, fc4_w, fc4_b, out);
}

// Round 4
// 392.003 us; speedup vs baseline: 2.5607x; 1.3963x over previous
//
#include <hip/hip_runtime.h>
#include <math.h>

#define CH 256   // IN_CH == HID == 256

typedef short bf16x8 __attribute__((ext_vector_type(8)));
typedef float f32x4 __attribute__((ext_vector_type(4)));
typedef unsigned int u32;

__device__ __forceinline__ unsigned short f2bf(float f) {
    u32 u = __float_as_uint(f);
    u += 0x7FFFu + ((u >> 16) & 1u);   // RNE
    return (unsigned short)(u >> 16);
}
__device__ __forceinline__ float bf2f(unsigned short h) {
    return __uint_as_float(((u32)h) << 16);
}
__device__ __forceinline__ void async16(const void* g, void* l) {
    __builtin_amdgcn_global_load_lds((const __attribute__((address_space(1))) u32*)g,
                                     (__attribute__((address_space(3))) u32*)l, 16, 0, 0);
}

// ---------------------------------------------------------------------------
// 1. Histogram
// ---------------------------------------------------------------------------
__global__ void hist_kernel(const int* __restrict__ ei,
                            unsigned* __restrict__ cnt_src,
                            unsigned* __restrict__ cnt_dst, int E) {
    int i = blockIdx.x * blockDim.x + threadIdx.x;
    int stride = gridDim.x * blockDim.x;
    for (; i < E; i += stride) {
        atomicAdd(&cnt_src[ei[i]], 1u);
        atomicAdd(&cnt_dst[ei[E + i]], 1u);
    }
}

// ---------------------------------------------------------------------------
// 2a/2b/2c. Parallel scan of cnt_dst -> row_ptr/cursor ; dinv = rsqrt(deg)
// ---------------------------------------------------------------------------
__global__ __launch_bounds__(256) void scan_p1(const unsigned* __restrict__ cnt_dst,
                                               unsigned* __restrict__ bsum, int N) {
    int b = blockIdx.x, t = threadIdx.x;
    int base = b * 1024 + t * 4;
    unsigned s = 0;
#pragma unroll
    for (int j = 0; j < 4; j++) {
        int i = base + j;
        if (i < N) s += cnt_dst[i];
    }
#pragma unroll
    for (int off = 32; off; off >>= 1) s += __shfl_down(s, off, 64);
    __shared__ unsigned wsum[4];
    if ((t & 63) == 0) wsum[t >> 6] = s;
    __syncthreads();
    if (t == 0) bsum[b] = wsum[0] + wsum[1] + wsum[2] + wsum[3];
}

__global__ void scan_p2(const unsigned* __restrict__ bsum,
                        unsigned* __restrict__ bbase,
                        unsigned* __restrict__ row_ptr, int B, int N) {
    if (threadIdx.x == 0 && blockIdx.x == 0) {
        unsigned run = 0;
        for (int b = 0; b < B; b++) { bbase[b] = run; run += bsum[b]; }
        row_ptr[N] = run;
    }
}

__global__ __launch_bounds__(256) void scan_p3(const unsigned* __restrict__ cnt_src,
                                               const unsigned* __restrict__ cnt_dst,
                                               const unsigned* __restrict__ bbase,
                                               unsigned* __restrict__ row_ptr,
                                               unsigned* __restrict__ cursor,
                                               float* __restrict__ dinv, int N) {
    int b = blockIdx.x, t = threadIdx.x;
    int base = b * 1024 + t * 4;
    unsigned v[4];
    unsigned tot = 0;
#pragma unroll
    for (int j = 0; j < 4; j++) {
        int i = base + j;
        v[j] = (i < N) ? cnt_dst[i] : 0u;
        tot += v[j];
    }
    __shared__ unsigned sc[256];
    sc[t] = tot;
    __syncthreads();
    for (int off = 1; off < 256; off <<= 1) {
        unsigned x = (t >= off) ? sc[t - off] : 0u;
        __syncthreads();
        sc[t] += x;
        __syncthreads();
    }
    unsigned run = (t ? sc[t - 1] : 0u) + bbase[b];
#pragma unroll
    for (int j = 0; j < 4; j++) {
        int i = base + j;
        if (i < N) {
            row_ptr[i] = run;
            cursor[i]  = run;
            run += v[j];
            dinv[i] = rsqrtf((float)(cnt_src[i] + 1u));
        }
    }
}

// ---------------------------------------------------------------------------
// 3. CSR fill
// ---------------------------------------------------------------------------
__global__ void fill_kernel(const int* __restrict__ ei,
                            unsigned* __restrict__ cursor,
                            unsigned* __restrict__ col, int E) {
    int i = blockIdx.x * blockDim.x + threadIdx.x;
    int stride = gridDim.x * blockDim.x;
    for (; i < E; i += stride) {
        int d = ei[E + i];
        unsigned pos = atomicAdd(&cursor[d], 1u);
        col[pos] = (unsigned)ei[i];
    }
}

// ---------------------------------------------------------------------------
// 4a. Cast x -> bf16 (8 elements per thread)
// ---------------------------------------------------------------------------
__global__ __launch_bounds__(256) void cast_x_kernel(const float* __restrict__ x,
                                                     unsigned short* __restrict__ xb,
                                                     long long total8) {
    long long i = (long long)blockIdx.x * blockDim.x + threadIdx.x;
    if (i >= total8) return;
    const float4* src = (const float4*)x;
    float4 a = src[i * 2], b = src[i * 2 + 1];
    ushort4 o0, o1;
    o0.x = f2bf(a.x); o0.y = f2bf(a.y); o0.z = f2bf(a.z); o0.w = f2bf(a.w);
    o1.x = f2bf(b.x); o1.y = f2bf(b.y); o1.z = f2bf(b.z); o1.w = f2bf(b.w);
    ((ushort4*)xb)[i * 2]     = o0;
    ((ushort4*)xb)[i * 2 + 1] = o1;
}

// ---------------------------------------------------------------------------
// 4b. Split W into bf16 hi+lo, TRANSPOSED to [n][k]
// ---------------------------------------------------------------------------
__global__ __launch_bounds__(256) void cast_w_kernel(const float* __restrict__ W,
                                                     unsigned short* __restrict__ whiT,
                                                     unsigned short* __restrict__ wloT) {
    int n = blockIdx.x;     // 256 blocks
    int k = threadIdx.x;    // 256 threads
    float w = W[(size_t)k * CH + n];
    unsigned short hi = f2bf(w);
    unsigned short lo = f2bf(w - bf2f(hi));
    whiT[(size_t)n * CH + k] = hi;
    wloT[(size_t)n * CH + k] = lo;
}

// ---------------------------------------------------------------------------
// 4c. MFMA GEMM: y_bf16 = bf16( dinv[:,None] * (x_bf @ (W_hi + W_lo)) )
//     128x128 tile / block, 4 waves x (4x4) 16x16x32 mfma tiles, BK=32,
//     global_load_lds width-16 staging, 24 KB LDS.
// ---------------------------------------------------------------------------
__global__ __launch_bounds__(256) void gemm_mfma(const unsigned short* __restrict__ xb,
                                                 const unsigned short* __restrict__ whiT,
                                                 const unsigned short* __restrict__ wloT,
                                                 const float* __restrict__ dinv,
                                                 unsigned short* __restrict__ y, int M) {
    __shared__ __align__(16) unsigned short smA [128 * 32];
    __shared__ __align__(16) unsigned short smBh[128 * 32];
    __shared__ __align__(16) unsigned short smBl[128 * 32];
    int t = threadIdx.x;
    int lane = t & 63, w = t >> 6;
    int m0 = blockIdx.x * 128;
    int n0 = blockIdx.y * 128;
    int mo = (w >> 1) * 64, no = (w & 1) * 64;
    int quad = lane >> 4, l16 = lane & 15;

    f32x4 acc[4][4] = {};

    // staging map: idx in [0,512): row = idx>>2, kq = idx&3 (16B quarter of 64B row)
    int idx0 = t, idx1 = t + 256;
    int rA0 = idx0 >> 2, kq0 = idx0 & 3;
    int rA1 = idx1 >> 2, kq1 = idx1 & 3;
    int gm0 = min(m0 + rA0, M - 1), gm1 = min(m0 + rA1, M - 1);
    size_t ga0 = (size_t)gm0 * CH + kq0 * 8;
    size_t ga1 = (size_t)gm1 * CH + kq1 * 8;
    size_t gb0 = (size_t)(n0 + rA0) * CH + kq0 * 8;
    size_t gb1 = (size_t)(n0 + rA1) * CH + kq1 * 8;

    for (int k0 = 0; k0 < CH; k0 += 32) {
        async16(&xb  [ga0 + k0], &smA [idx0 * 8]);
        async16(&xb  [ga1 + k0], &smA [idx1 * 8]);
        async16(&whiT[gb0 + k0], &smBh[idx0 * 8]);
        async16(&whiT[gb1 + k0], &smBh[idx1 * 8]);
        async16(&wloT[gb0 + k0], &smBl[idx0 * 8]);
        async16(&wloT[gb1 + k0], &smBl[idx1 * 8]);
        __syncthreads();

        bf16x8 a[4], bh[4], bl[4];
#pragma unroll
        for (int i = 0; i < 4; i++)
            a[i] = *(const bf16x8*)&smA[(mo + i * 16 + l16) * 32 + quad * 8];
#pragma unroll
        for (int j = 0; j < 4; j++) {
            bh[j] = *(const bf16x8*)&smBh[(no + j * 16 + l16) * 32 + quad * 8];
            bl[j] = *(const bf16x8*)&smBl[(no + j * 16 + l16) * 32 + quad * 8];
        }
#pragma unroll
        for (int i = 0; i < 4; i++)
#pragma unroll
            for (int j = 0; j < 4; j++) {
                acc[i][j] = __builtin_amdgcn_mfma_f32_16x16x32_bf16(a[i], bh[j], acc[i][j], 0, 0, 0);
                acc[i][j] = __builtin_amdgcn_mfma_f32_16x16x32_bf16(a[i], bl[j], acc[i][j], 0, 0, 0);
            }
        __syncthreads();
    }

    // epilogue: C/D layout col = lane&15, row = quad*4 + reg
#pragma unroll
    for (int i = 0; i < 4; i++) {
        int mbase = m0 + mo + i * 16 + quad * 4;
#pragma unroll
        for (int j = 0; j < 4; j++) {
            int ncol = n0 + no + j * 16 + l16;
#pragma unroll
            for (int r = 0; r < 4; r++) {
                int m = mbase + r;
                if (m < M)
                    y[(size_t)m * CH + ncol] = f2bf(dinv[m] * acc[i][j][r]);
            }
        }
    }
}

// ---------------------------------------------------------------------------
// 5. Fused gather + bias + relu + node-sum over bf16 y. One wave per node.
// ---------------------------------------------------------------------------
__global__ __launch_bounds__(256) void gather_kernel(const unsigned short* __restrict__ y,
                                                     const unsigned* __restrict__ row_ptr,
                                                     const unsigned* __restrict__ col,
                                                     const float* __restrict__ dinv,
                                                     const float* __restrict__ bias,
                                                     float* __restrict__ s_sum, int N) {
    int t = threadIdx.x;
    int lane = t & 63, wv = t >> 6;
    int gw = blockIdx.x * 4 + wv;
    int nw = gridDim.x * 4;
    float4 b4 = *(const float4*)&bias[lane * 4];
    float4 ts = make_float4(0.f, 0.f, 0.f, 0.f);
    const ushort4* yb = (const ushort4*)y;   // 64 ushort4 per node row

    for (int n = gw; n < N; n += nw) {
        unsigned rp0 = row_ptr[n], rp1 = row_ptr[n + 1];
        float dv = dinv[n];
        ushort4 sv = yb[(size_t)n * 64 + lane];   // self loop
        float4 a0 = make_float4(bf2f(sv.x), bf2f(sv.y), bf2f(sv.z), bf2f(sv.w));
        float4 a1 = make_float4(0.f, 0.f, 0.f, 0.f);
        unsigned e = rp0;
        for (; e + 1 < rp1; e += 2) {
            ushort4 v0 = yb[(size_t)col[e] * 64 + lane];
            ushort4 v1 = yb[(size_t)col[e + 1] * 64 + lane];
            a0.x += bf2f(v0.x); a0.y += bf2f(v0.y); a0.z += bf2f(v0.z); a0.w += bf2f(v0.w);
            a1.x += bf2f(v1.x); a1.y += bf2f(v1.y); a1.z += bf2f(v1.z); a1.w += bf2f(v1.w);
        }
        if (e < rp1) {
            ushort4 v0 = yb[(size_t)col[e] * 64 + lane];
            a0.x += bf2f(v0.x); a0.y += bf2f(v0.y); a0.z += bf2f(v0.z); a0.w += bf2f(v0.w);
        }
        float4 h;
        h.x = fmaxf(dv * (a0.x + a1.x) + b4.x, 0.f);
        h.y = fmaxf(dv * (a0.y + a1.y) + b4.y, 0.f);
        h.z = fmaxf(dv * (a0.z + a1.z) + b4.z, 0.f);
        h.w = fmaxf(dv * (a0.w + a1.w) + b4.w, 0.f);
        ts.x += h.x; ts.y += h.y; ts.z += h.z; ts.w += h.w;
    }

    __shared__ float red[1024];
    *(float4*)&red[wv * 256 + lane * 4] = ts;
    __syncthreads();
    if (t < 256) {
        atomicAdd(&s_sum[t], red[t] + red[256 + t] + red[512 + t] + red[768 + t]);
    }
}

// ---------------------------------------------------------------------------
// 6. Parallel FC: one wave per output element (768 waves).
// ---------------------------------------------------------------------------
__global__ __launch_bounds__(256) void fc_kernel(const float* __restrict__ s_sum,
                                                 const float* __restrict__ fc1_w, const float* __restrict__ fc1_b,
                                                 const float* __restrict__ fc2_w, const float* __restrict__ fc2_b,
                                                 const float* __restrict__ fc3_w, const float* __restrict__ fc3_b,
                                                 const float* __restrict__ fc4_w, const float* __restrict__ fc4_b,
                                                 float* __restrict__ out) {
    int wid  = (blockIdx.x * blockDim.x + threadIdx.x) >> 6;
    int lane = threadIdx.x & 63;
    if (wid >= 768) return;
    const float* w; const float* b; int row, obase;
    if (wid < 256)      { w = fc1_w; b = fc1_b; row = wid;       obase = 0;   }
    else if (wid < 512) { w = fc2_w; b = fc2_b; row = wid - 256; obase = 256; }
    else if (wid < 640) { w = fc3_w; b = fc3_b; row = wid - 512; obase = 512; }
    else                { w = fc4_w; b = fc4_b; row = wid - 640; obase = 640; }
    float4 wv = *(const float4*)&w[(size_t)row * 256 + lane * 4];
    float4 sv = *(const float4*)&s_sum[lane * 4];
    float d = wv.x * sv.x + wv.y * sv.y + wv.z * sv.z + wv.w * sv.w;
#pragma unroll
    for (int off = 32; off; off >>= 1) d += __shfl_down(d, off, 64);
    if (lane == 0) out[obase + row] = tanhf(d + b[row]);
}

// ---------------------------------------------------------------------------
extern "C" void kernel_launch(void* const* d_in, const int* in_sizes, int n_in,
                              void* d_out, int out_size, void* d_ws, size_t ws_size,
                              hipStream_t stream) {
    const float* x      = (const float*)d_in[0];
    const int*   ei     = (const int*)d_in[1];
    const float* conv_w = (const float*)d_in[2];
    const float* conv_b = (const float*)d_in[3];
    const float* fc1_w  = (const float*)d_in[4];
    const float* fc1_b  = (const float*)d_in[5];
    const float* fc2_w  = (const float*)d_in[6];
    const float* fc2_b  = (const float*)d_in[7];
    const float* fc3_w  = (const float*)d_in[8];
    const float* fc3_b  = (const float*)d_in[9];
    const float* fc4_w  = (const float*)d_in[10];
    const float* fc4_b  = (const float*)d_in[11];
    float* out = (float*)d_out;

    const int N = in_sizes[0] / CH;   // 50000
    const int E = in_sizes[1] / 2;    // 800000
    const int B = (N + 1023) / 1024;  // scan chunks (49)

    char* ws = (char*)d_ws;
    size_t off = 0;
    auto alloc = [&](size_t bytes) -> void* {
        off = (off + 255) & ~(size_t)255;
        void* p = ws + off;
        off += bytes;
        return p;
    };
    unsigned* cnt_src = (unsigned*)alloc((size_t)N * 4);
    unsigned* cnt_dst = (unsigned*)alloc((size_t)N * 4);
    unsigned* row_ptr = (unsigned*)alloc((size_t)(N + 1) * 4);
    unsigned* cursor  = (unsigned*)alloc((size_t)N * 4);
    float*    dinv    = (float*)alloc((size_t)N * 4);
    unsigned* col     = (unsigned*)alloc((size_t)E * 4);
    unsigned short* xb   = (unsigned short*)alloc((size_t)N * CH * 2);
    unsigned short* whiT = (unsigned short*)alloc((size_t)CH * CH * 2);
    unsigned short* wloT = (unsigned short*)alloc((size_t)CH * CH * 2);
    unsigned short* y    = (unsigned short*)alloc((size_t)N * CH * 2);
    float*    s_sum   = (float*)alloc((size_t)CH * 4);
    unsigned* bsum    = (unsigned*)alloc((size_t)B * 4);
    unsigned* bbase   = (unsigned*)alloc((size_t)B * 4);

    hipMemsetAsync(cnt_src, 0, (size_t)N * 4, stream);
    hipMemsetAsync(cnt_dst, 0, (size_t)N * 4, stream);
    hipMemsetAsync(s_sum,   0, (size_t)CH * 4, stream);

    hist_kernel<<<1024, 256, 0, stream>>>(ei, cnt_src, cnt_dst, E);
    scan_p1<<<B, 256, 0, stream>>>(cnt_dst, bsum, N);
    scan_p2<<<1, 64, 0, stream>>>(bsum, bbase, row_ptr, B, N);
    scan_p3<<<B, 256, 0, stream>>>(cnt_src, cnt_dst, bbase, row_ptr, cursor, dinv, N);
    fill_kernel<<<1024, 256, 0, stream>>>(ei, cursor, col, E);
    cast_x_kernel<<<(int)(((long long)N * CH / 8 + 255) / 256), 256, 0, stream>>>(x, xb, (long long)N * CH / 8);
    cast_w_kernel<<<CH, CH, 0, stream>>>(conv_w, whiT, wloT);
    dim3 ggrid((N + 127) / 128, 2);
    gemm_mfma<<<ggrid, 256, 0, stream>>>(xb, whiT, wloT, dinv, y, N);
    gather_kernel<<<1024, 256, 0, stream>>>(y, row_ptr, col, dinv, conv_b, s_sum, N);
    fc_kernel<<<192, 256, 0, stream>>>(s_sum,
                                       fc1_w, fc1_b, fc2_w, fc2_b,
                                       fc3_w, fc3_b, fc4_w, fc4_b, out);
}

// Round 5
// 376.994 us; speedup vs baseline: 2.6627x; 1.0398x over previous
//
#include <hip/hip_runtime.h>
#include <math.h>

#define CH 256   // IN_CH == HID == 256

typedef short bf16x8 __attribute__((ext_vector_type(8)));
typedef float f32x4 __attribute__((ext_vector_type(4)));
typedef unsigned int u32;

__device__ __forceinline__ unsigned short f2bf(float f) {
    u32 u = __float_as_uint(f);
    u += 0x7FFFu + ((u >> 16) & 1u);   // RNE
    return (unsigned short)(u >> 16);
}
__device__ __forceinline__ float bf2f(unsigned short h) {
    return __uint_as_float(((u32)h) << 16);
}
__device__ __forceinline__ float lo16f(u32 q) { return __uint_as_float(q << 16); }
__device__ __forceinline__ float hi16f(u32 q) { return __uint_as_float(q & 0xffff0000u); }
__device__ __forceinline__ void async16(const void* g, void* l) {
    __builtin_amdgcn_global_load_lds((const __attribute__((address_space(1))) u32*)g,
                                     (__attribute__((address_space(3))) u32*)l, 16, 0, 0);
}

// ---------------------------------------------------------------------------
// 1. prep: fused hist (cnt_src/cnt_dst) + cast_x (fp32->bf16) + cast_w (hi/lo,
//    transposed). Block-range split so the three run concurrently.
//    blocks [0,1024): cast_x ; [1024,1536): hist ; [1536,1600): cast_w
// ---------------------------------------------------------------------------
__global__ __launch_bounds__(256) void prep_kernel(const float* __restrict__ x,
                                                   unsigned short* __restrict__ xb,
                                                   const int* __restrict__ ei,
                                                   unsigned* __restrict__ cnt_src,
                                                   unsigned* __restrict__ cnt_dst,
                                                   const float* __restrict__ W,
                                                   unsigned short* __restrict__ whiT,
                                                   unsigned short* __restrict__ wloT,
                                                   int N, int E) {
    int b = blockIdx.x, t = threadIdx.x;
    if (b < 1024) {
        // cast_x: 8 floats per thread, grid-stride
        long long total8 = (long long)N * CH / 8;
        long long i = (long long)b * 256 + t;
        long long stride = 1024LL * 256;
        const float4* src = (const float4*)x;
        for (; i < total8; i += stride) {
            float4 a = src[i * 2], c = src[i * 2 + 1];
            ushort4 o0, o1;
            o0.x = f2bf(a.x); o0.y = f2bf(a.y); o0.z = f2bf(a.z); o0.w = f2bf(a.w);
            o1.x = f2bf(c.x); o1.y = f2bf(c.y); o1.z = f2bf(c.z); o1.w = f2bf(c.w);
            ((ushort4*)xb)[i * 2]     = o0;
            ((ushort4*)xb)[i * 2 + 1] = o1;
        }
    } else if (b < 1536) {
        int i = (b - 1024) * 256 + t;
        int stride = 512 * 256;
        for (; i < E; i += stride) {
            atomicAdd(&cnt_src[ei[i]], 1u);
            atomicAdd(&cnt_dst[ei[E + i]], 1u);
        }
    } else {
        int b2 = b - 1536;   // 0..63, each handles 4 output rows (n)
#pragma unroll
        for (int i = 0; i < 4; i++) {
            int n = b2 * 4 + i;
            float w = W[(size_t)t * CH + n];
            unsigned short hi = f2bf(w);
            unsigned short lo = f2bf(w - bf2f(hi));
            whiT[(size_t)n * CH + t] = hi;
            wloT[(size_t)n * CH + t] = lo;
        }
    }
}

// ---------------------------------------------------------------------------
// 2a. per-1024-chunk reduction of cnt_dst -> bsum[b]
// ---------------------------------------------------------------------------
__global__ __launch_bounds__(256) void scan_p1(const unsigned* __restrict__ cnt_dst,
                                               unsigned* __restrict__ bsum, int N) {
    int b = blockIdx.x, t = threadIdx.x;
    int base = b * 1024 + t * 4;
    unsigned s = 0;
#pragma unroll
    for (int j = 0; j < 4; j++) {
        int i = base + j;
        if (i < N) s += cnt_dst[i];
    }
#pragma unroll
    for (int off = 32; off; off >>= 1) s += __shfl_down(s, off, 64);
    __shared__ unsigned wsum[4];
    if ((t & 63) == 0) wsum[t >> 6] = s;
    __syncthreads();
    if (t == 0) bsum[b] = wsum[0] + wsum[1] + wsum[2] + wsum[3];
}

// ---------------------------------------------------------------------------
// 2b. per-chunk exclusive scan (block base computed inline from bsum) + dinv
// ---------------------------------------------------------------------------
__global__ __launch_bounds__(256) void scan_p3(const unsigned* __restrict__ cnt_src,
                                               const unsigned* __restrict__ cnt_dst,
                                               const unsigned* __restrict__ bsum,
                                               unsigned* __restrict__ row_ptr,
                                               unsigned* __restrict__ cursor,
                                               float* __restrict__ dinv, int N) {
    int b = blockIdx.x, t = threadIdx.x;
    __shared__ unsigned sbase;
    if (t == 0) {
        unsigned run = 0;
        for (int i = 0; i < b; i++) run += bsum[i];
        sbase = run;
        if (b == (int)gridDim.x - 1) {
            unsigned tot = run;
            for (int i = b; i < (int)gridDim.x; i++) tot += bsum[i];
            row_ptr[N] = tot;
        }
    }
    int base = b * 1024 + t * 4;
    unsigned v[4];
    unsigned tot = 0;
#pragma unroll
    for (int j = 0; j < 4; j++) {
        int i = base + j;
        v[j] = (i < N) ? cnt_dst[i] : 0u;
        tot += v[j];
    }
    __shared__ unsigned sc[256];
    sc[t] = tot;
    __syncthreads();
    for (int off = 1; off < 256; off <<= 1) {
        unsigned x = (t >= off) ? sc[t - off] : 0u;
        __syncthreads();
        sc[t] += x;
        __syncthreads();
    }
    unsigned run = (t ? sc[t - 1] : 0u) + sbase;
#pragma unroll
    for (int j = 0; j < 4; j++) {
        int i = base + j;
        if (i < N) {
            row_ptr[i] = run;
            cursor[i]  = run;
            run += v[j];
            dinv[i] = rsqrtf((float)(cnt_src[i] + 1u));
        }
    }
}

// ---------------------------------------------------------------------------
// 3. CSR fill
// ---------------------------------------------------------------------------
__global__ void fill_kernel(const int* __restrict__ ei,
                            unsigned* __restrict__ cursor,
                            unsigned* __restrict__ col, int E) {
    int i = blockIdx.x * blockDim.x + threadIdx.x;
    int stride = gridDim.x * blockDim.x;
    for (; i < E; i += stride) {
        int d = ei[E + i];
        unsigned pos = atomicAdd(&cursor[d], 1u);
        col[pos] = (unsigned)ei[i];
    }
}

// ---------------------------------------------------------------------------
// 4. MFMA GEMM: y_bf16 = bf16( dinv[:,None] * (x_bf @ (W_hi + W_lo)) )
// ---------------------------------------------------------------------------
__global__ __launch_bounds__(256) void gemm_mfma(const unsigned short* __restrict__ xb,
                                                 const unsigned short* __restrict__ whiT,
                                                 const unsigned short* __restrict__ wloT,
                                                 const float* __restrict__ dinv,
                                                 unsigned short* __restrict__ y, int M) {
    __shared__ __align__(16) unsigned short smA [128 * 32];
    __shared__ __align__(16) unsigned short smBh[128 * 32];
    __shared__ __align__(16) unsigned short smBl[128 * 32];
    int t = threadIdx.x;
    int lane = t & 63, w = t >> 6;
    int m0 = blockIdx.x * 128;
    int n0 = blockIdx.y * 128;
    int mo = (w >> 1) * 64, no = (w & 1) * 64;
    int quad = lane >> 4, l16 = lane & 15;

    f32x4 acc[4][4] = {};

    int idx0 = t, idx1 = t + 256;
    int rA0 = idx0 >> 2, kq0 = idx0 & 3;
    int rA1 = idx1 >> 2, kq1 = idx1 & 3;
    int gm0 = min(m0 + rA0, M - 1), gm1 = min(m0 + rA1, M - 1);
    size_t ga0 = (size_t)gm0 * CH + kq0 * 8;
    size_t ga1 = (size_t)gm1 * CH + kq1 * 8;
    size_t gb0 = (size_t)(n0 + rA0) * CH + kq0 * 8;
    size_t gb1 = (size_t)(n0 + rA1) * CH + kq1 * 8;

    for (int k0 = 0; k0 < CH; k0 += 32) {
        async16(&xb  [ga0 + k0], &smA [idx0 * 8]);
        async16(&xb  [ga1 + k0], &smA [idx1 * 8]);
        async16(&whiT[gb0 + k0], &smBh[idx0 * 8]);
        async16(&whiT[gb1 + k0], &smBh[idx1 * 8]);
        async16(&wloT[gb0 + k0], &smBl[idx0 * 8]);
        async16(&wloT[gb1 + k0], &smBl[idx1 * 8]);
        __syncthreads();

        bf16x8 a[4], bh[4], bl[4];
#pragma unroll
        for (int i = 0; i < 4; i++)
            a[i] = *(const bf16x8*)&smA[(mo + i * 16 + l16) * 32 + quad * 8];
#pragma unroll
        for (int j = 0; j < 4; j++) {
            bh[j] = *(const bf16x8*)&smBh[(no + j * 16 + l16) * 32 + quad * 8];
            bl[j] = *(const bf16x8*)&smBl[(no + j * 16 + l16) * 32 + quad * 8];
        }
#pragma unroll
        for (int i = 0; i < 4; i++)
#pragma unroll
            for (int j = 0; j < 4; j++) {
                acc[i][j] = __builtin_amdgcn_mfma_f32_16x16x32_bf16(a[i], bh[j], acc[i][j], 0, 0, 0);
                acc[i][j] = __builtin_amdgcn_mfma_f32_16x16x32_bf16(a[i], bl[j], acc[i][j], 0, 0, 0);
            }
        __syncthreads();
    }

#pragma unroll
    for (int i = 0; i < 4; i++) {
        int mbase = m0 + mo + i * 16 + quad * 4;
#pragma unroll
        for (int j = 0; j < 4; j++) {
            int ncol = n0 + no + j * 16 + l16;
#pragma unroll
            for (int r = 0; r < 4; r++) {
                int m = mbase + r;
                if (m < M)
                    y[(size_t)m * CH + ncol] = f2bf(dinv[m] * acc[i][j][r]);
            }
        }
    }
}

// ---------------------------------------------------------------------------
// 5. Gather + bias + relu + node-sum. Wave per node; half-wave per row
//    (16 B/lane), 4 rows in flight (u-unroll), self-loop as pad row.
// ---------------------------------------------------------------------------
__global__ __launch_bounds__(256) void gather_kernel(const unsigned short* __restrict__ y,
                                                     const unsigned* __restrict__ row_ptr,
                                                     const unsigned* __restrict__ col,
                                                     const float* __restrict__ dinv,
                                                     const float* __restrict__ bias,
                                                     float* __restrict__ s_sum, int N) {
    int t = threadIdx.x;
    int lane = t & 63, wv = t >> 6;
    int half = lane >> 5;      // which row of the pair this lane reads
    int l32  = lane & 31;      // 8-channel group (16 B)
    int gw = blockIdx.x * 4 + wv;
    int nw = gridDim.x * 4;

    float b8[8];
#pragma unroll
    for (int j = 0; j < 8; j++) b8[j] = bias[l32 * 8 + j];

    float ts[8] = {0.f, 0.f, 0.f, 0.f, 0.f, 0.f, 0.f, 0.f};
    float hm = (half == 0) ? 1.f : 0.f;   // only half 0 accumulates ts

    for (int n = gw; n < N; n += nw) {
        unsigned rp0 = row_ptr[n];
        unsigned deg = row_ptr[n + 1] - rp0;
        unsigned cnt = deg + 1;            // + self loop
        float acc[8] = {0.f, 0.f, 0.f, 0.f, 0.f, 0.f, 0.f, 0.f};

        for (unsigned k = 0; k < cnt; k += 4) {
#pragma unroll
            for (int u = 0; u < 2; u++) {
                unsigned r = k + u * 2 + half;
                unsigned src = (r < deg) ? col[rp0 + r] : (unsigned)n;  // r==deg -> self
                float m = (r < cnt) ? 1.f : 0.f;
                uint4 q = *(const uint4*)(y + ((size_t)src << 8) + (l32 << 3));
                acc[0] = fmaf(m, lo16f(q.x), acc[0]);
                acc[1] = fmaf(m, hi16f(q.x), acc[1]);
                acc[2] = fmaf(m, lo16f(q.y), acc[2]);
                acc[3] = fmaf(m, hi16f(q.y), acc[3]);
                acc[4] = fmaf(m, lo16f(q.z), acc[4]);
                acc[5] = fmaf(m, hi16f(q.z), acc[5]);
                acc[6] = fmaf(m, lo16f(q.w), acc[6]);
                acc[7] = fmaf(m, hi16f(q.w), acc[7]);
            }
        }
        float dv = dinv[n];
#pragma unroll
        for (int j = 0; j < 8; j++) {
            float v = acc[j] + __shfl_xor(acc[j], 32, 64);
            float h = fmaxf(fmaf(dv, v, b8[j]), 0.f);
            ts[j] = fmaf(hm, h, ts[j]);
        }
    }

    __shared__ float red[1024];
    if (half == 0) {
#pragma unroll
        for (int j = 0; j < 8; j++) red[wv * 256 + l32 * 8 + j] = ts[j];
    }
    __syncthreads();
    atomicAdd(&s_sum[t], red[t] + red[256 + t] + red[512 + t] + red[768 + t]);
}

// ---------------------------------------------------------------------------
// 6. Parallel FC: one wave per output element (768 waves).
// ---------------------------------------------------------------------------
__global__ __launch_bounds__(256) void fc_kernel(const float* __restrict__ s_sum,
                                                 const float* __restrict__ fc1_w, const float* __restrict__ fc1_b,
                                                 const float* __restrict__ fc2_w, const float* __restrict__ fc2_b,
                                                 const float* __restrict__ fc3_w, const float* __restrict__ fc3_b,
                                                 const float* __restrict__ fc4_w, const float* __restrict__ fc4_b,
                                                 float* __restrict__ out) {
    int wid  = (blockIdx.x * blockDim.x + threadIdx.x) >> 6;
    int lane = threadIdx.x & 63;
    if (wid >= 768) return;
    const float* w; const float* b; int row, obase;
    if (wid < 256)      { w = fc1_w; b = fc1_b; row = wid;       obase = 0;   }
    else if (wid < 512) { w = fc2_w; b = fc2_b; row = wid - 256; obase = 256; }
    else if (wid < 640) { w = fc3_w; b = fc3_b; row = wid - 512; obase = 512; }
    else                { w = fc4_w; b = fc4_b; row = wid - 640; obase = 640; }
    float4 wv = *(const float4*)&w[(size_t)row * 256 + lane * 4];
    float4 sv = *(const float4*)&s_sum[lane * 4];
    float d = wv.x * sv.x + wv.y * sv.y + wv.z * sv.z + wv.w * sv.w;
#pragma unroll
    for (int off = 32; off; off >>= 1) d += __shfl_down(d, off, 64);
    if (lane == 0) out[obase + row] = tanhf(d + b[row]);
}

// ---------------------------------------------------------------------------
extern "C" void kernel_launch(void* const* d_in, const int* in_sizes, int n_in,
                              void* d_out, int out_size, void* d_ws, size_t ws_size,
                              hipStream_t stream) {
    const float* x      = (const float*)d_in[0];
    const int*   ei     = (const int*)d_in[1];
    const float* conv_w = (const float*)d_in[2];
    const float* conv_b = (const float*)d_in[3];
    const float* fc1_w  = (const float*)d_in[4];
    const float* fc1_b  = (const float*)d_in[5];
    const float* fc2_w  = (const float*)d_in[6];
    const float* fc2_b  = (const float*)d_in[7];
    const float* fc3_w  = (const float*)d_in[8];
    const float* fc3_b  = (const float*)d_in[9];
    const float* fc4_w  = (const float*)d_in[10];
    const float* fc4_b  = (const float*)d_in[11];
    float* out = (float*)d_out;

    const int N = in_sizes[0] / CH;   // 50000
    const int E = in_sizes[1] / 2;    // 800000
    const int B = (N + 1023) / 1024;  // scan chunks (49)

    char* ws = (char*)d_ws;
    size_t off = 0;
    auto alloc = [&](size_t bytes) -> void* {
        off = (off + 255) & ~(size_t)255;
        void* p = ws + off;
        off += bytes;
        return p;
    };
    // zeroed region first (single memset): cnt_src, cnt_dst, s_sum
    unsigned* cnt_src = (unsigned*)alloc((size_t)N * 4);
    unsigned* cnt_dst = (unsigned*)alloc((size_t)N * 4);
    float*    s_sum   = (float*)alloc((size_t)CH * 4);
    size_t zero_bytes = off;   // everything from ws start
    unsigned* row_ptr = (unsigned*)alloc((size_t)(N + 1) * 4);
    unsigned* cursor  = (unsigned*)alloc((size_t)N * 4);
    float*    dinv    = (float*)alloc((size_t)N * 4);
    unsigned* col     = (unsigned*)alloc((size_t)E * 4);
    unsigned short* xb   = (unsigned short*)alloc((size_t)N * CH * 2);
    unsigned short* whiT = (unsigned short*)alloc((size_t)CH * CH * 2);
    unsigned short* wloT = (unsigned short*)alloc((size_t)CH * CH * 2);
    unsigned short* y    = (unsigned short*)alloc((size_t)N * CH * 2);
    unsigned* bsum    = (unsigned*)alloc((size_t)B * 4);

    hipMemsetAsync(ws, 0, zero_bytes, stream);

    prep_kernel<<<1600, 256, 0, stream>>>(x, xb, ei, cnt_src, cnt_dst,
                                          conv_w, whiT, wloT, N, E);
    scan_p1<<<B, 256, 0, stream>>>(cnt_dst, bsum, N);
    scan_p3<<<B, 256, 0, stream>>>(cnt_src, cnt_dst, bsum, row_ptr, cursor, dinv, N);
    fill_kernel<<<1024, 256, 0, stream>>>(ei, cursor, col, E);
    dim3 ggrid((N + 127) / 128, 2);
    gemm_mfma<<<ggrid, 256, 0, stream>>>(xb, whiT, wloT, dinv, y, N);
    gather_kernel<<<2048, 256, 0, stream>>>(y, row_ptr, col, dinv, conv_b, s_sum, N);
    fc_kernel<<<192, 256, 0, stream>>>(s_sum,
                                       fc1_w, fc1_b, fc2_w, fc2_b,
                                       fc3_w, fc3_b, fc4_w, fc4_b, out);
}